// Round 23
// baseline (282.515 us; speedup 1.0000x reference)
//
#include <hip/hip_runtime.h>

// ---------------------------------------------------------------------------
// MultiHeadAttention. cast_all (x + 4 weights + rope table, ONE launch),
// 3 serial ring-GEMM projections (Q+RoPE, K+RoPE fused epilogues; V^T),
// attn_lds2 (2-wave shared-tile, defer-lsum, CU-BALANCED p-permutation),
// ring-GEMM out.
// R22 lever: 1024 blocks = exactly 4/CU all-resident -> duration = max per-CU
// load. Old p=31-j gave per-CU tile sums 104..160; permutation
// p = 8k + (k odd ? 7-b : b) makes every CU sum exactly 132.
// ---------------------------------------------------------------------------

typedef unsigned short u16;
typedef unsigned int   u32;
typedef __attribute__((ext_vector_type(4)))  float f32x4;
typedef __attribute__((ext_vector_type(16))) float f32x16;
typedef __attribute__((ext_vector_type(8)))  short short8;
typedef __attribute__((ext_vector_type(4)))  u16   u16x4;
typedef __attribute__((ext_vector_type(2)))  u16   u16x2;

#define NB   2
#define NH   16
#define SEQ  2048
#define DK   128
#define EMB  2048

__device__ __forceinline__ u16 f2bf(float f) {
    union { float f; unsigned int u; } v; v.f = f;
    unsigned int r = v.u + 0x7FFFu + ((v.u >> 16) & 1u);   // RTNE
    return (u16)(r >> 16);
}
__device__ __forceinline__ float bf2f(u16 h) {
    union { unsigned int u; float f; } v; v.u = ((unsigned int)h) << 16;
    return v.f;
}
__device__ __forceinline__ f32x4 mfma16(short8 a, short8 b, f32x4 c) {
    return __builtin_amdgcn_mfma_f32_16x16x32_bf16(a, b, c, 0, 0, 0);
}
__device__ __forceinline__ f32x16 mfma32(short8 a, short8 b, f32x16 c) {
    return __builtin_amdgcn_mfma_f32_32x32x16_bf16(a, b, c, 0, 0, 0);
}

#define GLDS(gsrc, ldst) __builtin_amdgcn_global_load_lds( \
    (const __attribute__((address_space(1))) void*)(gsrc), \
    (__attribute__((address_space(3))) void*)(ldst), 16, 0, 0)

// ---------------------------------------------------------------------------
// fused cast + rope table: blocks [0,24576) cast x/wq/wk/wv/wo (4 f32/thread);
// blocks [24576,25088) build ct/st (1 entry/thread, 131072 entries).
__global__ __launch_bounds__(256) void cast_all(const float* __restrict__ x,
                                                const float* __restrict__ wq,
                                                const float* __restrict__ wk,
                                                const float* __restrict__ wv,
                                                const float* __restrict__ wo,
                                                const float* __restrict__ freq,
                                                u16* __restrict__ xb,
                                                u16* __restrict__ oq, u16* __restrict__ ok,
                                                u16* __restrict__ ov, u16* __restrict__ oo,
                                                float* __restrict__ ct,
                                                float* __restrict__ st) {
    int i = blockIdx.x * 256 + threadIdx.x;
    if (i >= 6291456) {                              // rope table tail
        int j = i - 6291456;                         // 0..131071
        int s = j >> 6, d2 = j & 63;
        float pe = freq[s * DK + d2 * 2];
        ct[j] = cosf(pe);
        st[j] = sinf(pe);
        return;
    }
    const float* src;
    u16* dst;
    int idx;
    if (i < 2097152) { src = x; dst = xb; idx = i; }
    else {
        int j = i - 2097152;
        int sel = j >> 20;
        idx = j & 1048575;
        src = (sel == 0) ? wq : (sel == 1) ? wk : (sel == 2) ? wv : wo;
        dst = (sel == 0) ? oq : (sel == 1) ? ok : (sel == 2) ? ov : oo;
    }
    f32x4 v = ((const f32x4*)src)[idx];
    u16x4 o;
    o[0] = f2bf(v[0]); o[1] = f2bf(v[1]); o[2] = f2bf(v[2]); o[3] = f2bf(v[3]);
    ((u16x4*)dst)[idx] = o;
}

// ---------------------------------------------------------------------------
// HW-verified (R4 probe) ring-3 GEMM: C[m][n] = sum_k A[m][k]*B[n][k].
// MODE 1: bf16 (b,h,d,s). MODE 3: f32 row-major. MODE 6: (b,h,s,d)+RoPE.
template <int MODE>
__global__ __launch_bounds__(256) void gemm_ring(const u16* __restrict__ A,
                                                 const u16* __restrict__ B,
                                                 void* __restrict__ Cout,
                                                 int M, int N, int K,
                                                 const float* __restrict__ ct,
                                                 const float* __restrict__ st) {
    __shared__ __align__(16) u16 As[3 * 4096];
    __shared__ __align__(16) u16 Bs[3 * 4096];
    const int tid  = threadIdx.x;
    const int lane = tid & 63;
    const int wid  = tid >> 6;
    const int wm   = wid >> 1, wn = wid & 1;
    const int nwgx = (int)gridDim.x;
    const int wgid = (int)blockIdx.y * nwgx + (int)blockIdx.x;
    const int cpx  = (nwgx * (int)gridDim.y) >> 3;
    const int swz  = (wgid & 7) * cpx + (wgid >> 3);
    const int m0   = (swz % nwgx) * 128, n0 = (swz / nwgx) * 128;
    const int lr   = lane & 15, lk = lane >> 4;

    const u16* Asrc = A + (size_t)(m0 + (tid >> 2)) * K + (tid & 3) * 8;
    const u16* Bsrc = B + (size_t)(n0 + (tid >> 2)) * K + (tid & 3) * 8;
    const int  dst0 = wid * 512;

    f32x4 acc[4][4] = {};
    const int NT = K >> 5;

#pragma unroll
    for (int i = 0; i < 2; ++i) {
        GLDS(Asrc + (size_t)i * 64 * K,      &As[i * 2048 + dst0]);
        GLDS(Bsrc + (size_t)i * 64 * K,      &Bs[i * 2048 + dst0]);
    }
#pragma unroll
    for (int i = 0; i < 2; ++i) {
        GLDS(Asrc + (size_t)i * 64 * K + 32, &As[4096 + i * 2048 + dst0]);
        GLDS(Bsrc + (size_t)i * 64 * K + 32, &Bs[4096 + i * 2048 + dst0]);
    }

    int buf = 0;
    for (int t = 0; t < NT; ++t) {
        if (t < NT - 1) asm volatile("s_waitcnt vmcnt(4)" ::: "memory");
        else            asm volatile("s_waitcnt vmcnt(0)" ::: "memory");
        __builtin_amdgcn_s_barrier();

        short8 af[4], bf[4];
#pragma unroll
        for (int i = 0; i < 4; ++i)
            af[i] = *(const short8*)&As[buf * 4096 + (wm * 64 + i * 16 + lr) * 32 + lk * 8];
#pragma unroll
        for (int j = 0; j < 4; ++j)
            bf[j] = *(const short8*)&Bs[buf * 4096 + (wn * 64 + j * 16 + lr) * 32 + lk * 8];

        if (t + 2 < NT) {
            int b2 = buf + 2; if (b2 >= 3) b2 -= 3;
            const u16* a2  = Asrc + (size_t)(t + 2) * 32;
            const u16* b2p = Bsrc + (size_t)(t + 2) * 32;
#pragma unroll
            for (int i = 0; i < 2; ++i) {
                GLDS(a2  + (size_t)i * 64 * K, &As[b2 * 4096 + i * 2048 + dst0]);
                GLDS(b2p + (size_t)i * 64 * K, &Bs[b2 * 4096 + i * 2048 + dst0]);
            }
        }

        __builtin_amdgcn_s_setprio(1);
#pragma unroll
        for (int i = 0; i < 4; ++i)
#pragma unroll
            for (int j = 0; j < 4; ++j)
                acc[i][j] = mfma16(af[i], bf[j], acc[i][j]);
        __builtin_amdgcn_s_setprio(0);

        buf = (buf == 2) ? 0 : buf + 1;
    }

#pragma unroll
    for (int i = 0; i < 4; ++i) {
#pragma unroll
        for (int j = 0; j < 4; ++j) {
#pragma unroll
            for (int r = 0; r < 4; ++r) {
                int m = m0 + wm * 64 + i * 16 + lk * 4 + r;
                int n = n0 + wn * 64 + j * 16 + lr;
                float v = acc[i][j][r];
                if (MODE == 1) {        // (b,h,d,s)
                    int h = m >> 7, d = m & (DK - 1), b = n >> 11, s = n & (SEQ - 1);
                    ((u16*)Cout)[(((size_t)(b * NH + h) * DK + d) * SEQ) + s] = f2bf(v);
                } else if (MODE == 6) { // (b,h,s,d) with fused RoPE
                    int b = m >> 11, s = m & (SEQ - 1), h = n >> 7, d = n & (DK - 1);
                    float part = __shfl_xor(v, 1);
                    int ti = (s << 6) + (d >> 1);
                    float c = ct[ti], sn = st[ti];
                    float vr = (lr & 1) ? (v * c + part * sn) : (v * c - part * sn);
                    ((u16*)Cout)[(((size_t)(b * NH + h) * SEQ + s) * DK) + d] = f2bf(vr);
                } else {                // f32 row-major
                    ((float*)Cout)[(size_t)m * N + n] = v;
                }
            }
        }
    }
}

// ---------------------------------------------------------------------------
// R13-HW-verified 2-wave shared-tile flash attention + defer-lsum.
// p-permutation: jj = gid>>5, b = jj&7, k = jj>>3,
// p = 8k + (k odd ? 7-b : b)  -> every CU's 4 resident blocks sum to 132 tiles.
__global__ __launch_bounds__(128, 2) void attn_lds2(const u16* __restrict__ Q,
                                                    const u16* __restrict__ K,
                                                    const u16* __restrict__ VT,
                                                    u16* __restrict__ O) {
    const int gid  = blockIdx.x;               // 1024
    const int bh   = (gid & 7) * 4 + ((gid >> 3) & 3);
    const int jj   = gid >> 5;                 // 0..31
    const int bq   = jj & 7, kq4 = jj >> 3;
    const int p    = 8 * kq4 + ((kq4 & 1) ? (7 - bq) : bq);   // balanced perm
    const int tid  = threadIdx.x;
    const int w    = tid >> 6;
    const int l    = tid & 63;
    const int q32  = l & 31;
    const int half = l >> 5;
    const int qc   = 2 * p + w;
    const int nt   = 2 * p + 2;
    const int q0   = qc * 32;

    __shared__ __align__(16) u16 Ksh[2][4096];
    __shared__ __align__(16) u16 Vsh[2][4096];

    const u16* Kg  = K  + (size_t)bh * SEQ * DK;
    const u16* VTg = VT + (size_t)bh * DK * SEQ;
    const int b = bh >> 4, h = bh & 15;

    auto stage = [&](int t, int bufn) {
#pragma unroll
        for (int i = 0; i < 4; ++i) {
            int cid = i * 128 + w * 64 + l;
            int kr = cid >> 4, kc = cid & 15;
            GLDS(Kg + (size_t)(t * 32 + kr) * DK + ((kc ^ (kr & 7)) * 8),
                 &Ksh[bufn][(i * 128 + w * 64) * 8]);
            int vr = cid >> 2, vc = cid & 3;
            GLDS(VTg + (size_t)vr * SEQ + t * 32 + ((vc ^ ((vr >> 1) & 3)) * 8),
                 &Vsh[bufn][(i * 128 + w * 64) * 8]);
        }
    };

    short8 qf[8];
    {
        const u16* Qg = Q + ((size_t)bh * SEQ + q0) * DK;
#pragma unroll
        for (int kq = 0; kq < 8; ++kq)
            qf[kq] = *(const short8*)(Qg + q32 * DK + kq * 16 + half * 8);
    }

    f32x16 oacc[4] = {};
    float m = -INFINITY, lsum = 0.f;           // lsum: this half only

    stage(0, 0);
    stage(1, 1);
    for (int t = 0; t < nt; ++t) {
        const int buf = t & 1;
        if (t + 1 < nt) asm volatile("s_waitcnt vmcnt(8)" ::: "memory");
        else            asm volatile("s_waitcnt vmcnt(0)" ::: "memory");
        __builtin_amdgcn_s_barrier();
        __builtin_amdgcn_sched_barrier(0);

        if (t <= qc) {
            const float rs = 0.08838834764831845f;
            short8 kf[8], vf[8];
#pragma unroll
            for (int kq = 0; kq < 8; ++kq) {
                int c = (kq * 2 + half) ^ (q32 & 7);
                kf[kq] = *(const short8*)&Ksh[buf][q32 * 128 + c * 8];
            }
#pragma unroll
            for (int i = 0; i < 8; ++i) {
                int dblk = i >> 1, ch = i & 1;
                int vrow = dblk * 32 + q32;
                int c = (ch * 2 + half) ^ ((q32 >> 1) & 3);
                vf[i] = *(const short8*)&Vsh[buf][vrow * 32 + c * 8];
            }
            const bool diag = (t == qc);

            f32x16 sacc = {};
            __builtin_amdgcn_s_setprio(1);
#pragma unroll
            for (int kq = 0; kq < 8; ++kq) sacc = mfma32(kf[kq], qf[kq], sacc);
            __builtin_amdgcn_s_setprio(0);
#pragma unroll
            for (int r = 0; r < 16; ++r) {
                int kk = (r & 3) + 8 * (r >> 2) + 4 * half;
                float s = sacc[r] * rs;
                if (diag && kk > q32) s = -INFINITY;
                sacc[r] = s;
            }
            float mx[8];
#pragma unroll
            for (int r = 0; r < 8; ++r) mx[r] = fmaxf(sacc[r], sacc[r + 8]);
#pragma unroll
            for (int r = 0; r < 4; ++r) mx[r] = fmaxf(mx[r], mx[r + 4]);
            float tmax = fmaxf(fmaxf(mx[0], mx[1]), fmaxf(mx[2], mx[3]));
            tmax = fmaxf(tmax, __shfl_xor(tmax, 32));
            if (__any(tmax - m > 8.0f)) {
                float mn = fmaxf(m, tmax);
                float sc = __expf(m - mn);
                m = mn; lsum *= sc;
#pragma unroll
                for (int d = 0; d < 4; ++d)
#pragma unroll
                    for (int r = 0; r < 16; ++r) oacc[d][r] *= sc;
            }
#pragma unroll
            for (int r = 0; r < 16; ++r) sacc[r] = __expf(sacc[r] - m);
            float sm[8];
#pragma unroll
            for (int r = 0; r < 8; ++r) sm[r] = sacc[r] + sacc[r + 8];
#pragma unroll
            for (int r = 0; r < 4; ++r) sm[r] = sm[r] + sm[r + 4];
            lsum += (sm[0] + sm[1]) + (sm[2] + sm[3]);   // defer cross-half sum
            u32 pk[8];
#pragma unroll
            for (int i = 0; i < 8; ++i)
                pk[i] = ((u32)f2bf(sacc[2 * i + 1]) << 16) | (u32)f2bf(sacc[2 * i]);
            u32 s0 = __shfl_xor((int)pk[0], 32), s1 = __shfl_xor((int)pk[1], 32);
            u32 s2 = __shfl_xor((int)pk[2], 32), s3 = __shfl_xor((int)pk[3], 32);
            u32 s4 = __shfl_xor((int)pk[4], 32), s5 = __shfl_xor((int)pk[5], 32);
            u32 s6 = __shfl_xor((int)pk[6], 32), s7 = __shfl_xor((int)pk[7], 32);
            union { u32 wd[4]; short8 s8; } P0, P1;
            P0.wd[0] = half ? s2    : pk[0];  P0.wd[1] = half ? s3    : pk[1];
            P0.wd[2] = half ? pk[2] : s0;     P0.wd[3] = half ? pk[3] : s1;
            P1.wd[0] = half ? s6    : pk[4];  P1.wd[1] = half ? s7    : pk[5];
            P1.wd[2] = half ? pk[6] : s4;     P1.wd[3] = half ? pk[7] : s5;
            __builtin_amdgcn_s_setprio(1);
#pragma unroll
            for (int d = 0; d < 4; ++d) {
                oacc[d] = mfma32(vf[2 * d],     P0.s8, oacc[d]);
                oacc[d] = mfma32(vf[2 * d + 1], P1.s8, oacc[d]);
            }
            __builtin_amdgcn_s_setprio(0);
        }

        __builtin_amdgcn_s_barrier();
        if (t + 2 < nt) stage(t + 2, buf);
    }

    lsum += __shfl_xor(lsum, 32);              // combine halves once
    float inv = 1.0f / lsum;
    u16* Og = O + ((size_t)b * SEQ + q0 + q32) * EMB + h * DK;
#pragma unroll
    for (int d = 0; d < 4; ++d)
#pragma unroll
        for (int rq = 0; rq < 4; ++rq) {
            u16x4 o4;
#pragma unroll
            for (int j = 0; j < 4; ++j) o4[j] = f2bf(oacc[d][rq * 4 + j] * inv);
            *(u16x4*)(Og + d * 32 + rq * 8 + half * 4) = o4;
        }
}

// ---------------------------------------------------------------------------
extern "C" void kernel_launch(void* const* d_in, const int* in_sizes, int n_in,
                              void* d_out, int out_size, void* d_ws, size_t ws_size,
                              hipStream_t stream) {
    const float* x    = (const float*)d_in[0];
    const float* wq   = (const float*)d_in[1];
    const float* wk   = (const float*)d_in[2];
    const float* wv   = (const float*)d_in[3];
    const float* wo   = (const float*)d_in[4];
    const float* freq = (const float*)d_in[5];

    char* ws = (char*)d_ws;
    u16*  xb  = (u16*)(ws);                          // 16 MB; later attn output
    u16*  wqb = (u16*)(ws + 16777216);               //  8 MB
    u16*  wkb = (u16*)(ws + 25165824);               //  8 MB
    u16*  wvb = (u16*)(ws + 33554432);               //  8 MB
    u16*  wob = (u16*)(ws + 41943040);               //  8 MB (live till end)
    u16*  Qb  = (u16*)(ws + 50331648);               // 16 MB
    u16*  Kb  = (u16*)(ws + 67108864);               // 16 MB
    u16*  VTb = (u16*)(ws + 83886080);               // 16 MB
    float* ct = (float*)(ws + 100663296);
    float* st = (float*)(ws + 101187584);
    u16*  attn = xb;                                 // x dead after projections

    // casts + rope table, one launch
    cast_all<<<25088, 256, 0, stream>>>(x, wq, wk, wv, wo, freq,
                                        xb, wqb, wkb, wvb, wob, ct, st);

    // serial projections (L2-friendly): Q+RoPE, K+RoPE, V^T
    gemm_ring<6><<<dim3(32, 16), 256, 0, stream>>>(xb,  wqb, Qb,  4096, 2048, 2048, ct, st);
    gemm_ring<6><<<dim3(32, 16), 256, 0, stream>>>(xb,  wkb, Kb,  4096, 2048, 2048, ct, st);
    gemm_ring<1><<<dim3(16, 32), 256, 0, stream>>>(wvb, xb,  VTb, 2048, 4096, 2048, nullptr, nullptr);

    // attention: 2-wave shared-tile, defer-lsum, CU-balanced p-permutation
    attn_lds2<<<1024, 128, 0, stream>>>(Qb, Kb, VTb, attn);

    gemm_ring<3><<<dim3(32, 16), 256, 0, stream>>>(attn, wob, d_out, 4096, 2048, 2048, nullptr, nullptr);
}

// Round 24
// 278.932 us; speedup vs baseline: 1.0128x; 1.0128x over previous
//
#include <hip/hip_runtime.h>

// ---------------------------------------------------------------------------
// MultiHeadAttention — FINAL (R22 config, 279.7us session best).
// cast_all (x + 4 weights + rope table, ONE launch), 3 serial ring-GEMM
// projections (Q+RoPE, K+RoPE fused epilogues; V^T), attn_lds2 (2-wave
// shared-tile, defer-lsum, longest-first), ring-GEMM out.
// R23 lesson: CU-balance p-permutation regressed (+5us) -> reverted; the
// longest-first mapping is the empirical best of 8 dispatch orders tried.
// ---------------------------------------------------------------------------

typedef unsigned short u16;
typedef unsigned int   u32;
typedef __attribute__((ext_vector_type(4)))  float f32x4;
typedef __attribute__((ext_vector_type(16))) float f32x16;
typedef __attribute__((ext_vector_type(8)))  short short8;
typedef __attribute__((ext_vector_type(4)))  u16   u16x4;
typedef __attribute__((ext_vector_type(2)))  u16   u16x2;

#define NB   2
#define NH   16
#define SEQ  2048
#define DK   128
#define EMB  2048

__device__ __forceinline__ u16 f2bf(float f) {
    union { float f; unsigned int u; } v; v.f = f;
    unsigned int r = v.u + 0x7FFFu + ((v.u >> 16) & 1u);   // RTNE
    return (u16)(r >> 16);
}
__device__ __forceinline__ float bf2f(u16 h) {
    union { unsigned int u; float f; } v; v.u = ((unsigned int)h) << 16;
    return v.f;
}
__device__ __forceinline__ f32x4 mfma16(short8 a, short8 b, f32x4 c) {
    return __builtin_amdgcn_mfma_f32_16x16x32_bf16(a, b, c, 0, 0, 0);
}
__device__ __forceinline__ f32x16 mfma32(short8 a, short8 b, f32x16 c) {
    return __builtin_amdgcn_mfma_f32_32x32x16_bf16(a, b, c, 0, 0, 0);
}

#define GLDS(gsrc, ldst) __builtin_amdgcn_global_load_lds( \
    (const __attribute__((address_space(1))) void*)(gsrc), \
    (__attribute__((address_space(3))) void*)(ldst), 16, 0, 0)

// ---------------------------------------------------------------------------
// fused cast + rope table: blocks [0,24576) cast x/wq/wk/wv/wo (4 f32/thread);
// blocks [24576,25088) build ct/st (1 entry/thread, 131072 entries).
__global__ __launch_bounds__(256) void cast_all(const float* __restrict__ x,
                                                const float* __restrict__ wq,
                                                const float* __restrict__ wk,
                                                const float* __restrict__ wv,
                                                const float* __restrict__ wo,
                                                const float* __restrict__ freq,
                                                u16* __restrict__ xb,
                                                u16* __restrict__ oq, u16* __restrict__ ok,
                                                u16* __restrict__ ov, u16* __restrict__ oo,
                                                float* __restrict__ ct,
                                                float* __restrict__ st) {
    int i = blockIdx.x * 256 + threadIdx.x;
    if (i >= 6291456) {                              // rope table tail
        int j = i - 6291456;                         // 0..131071
        int s = j >> 6, d2 = j & 63;
        float pe = freq[s * DK + d2 * 2];
        ct[j] = cosf(pe);
        st[j] = sinf(pe);
        return;
    }
    const float* src;
    u16* dst;
    int idx;
    if (i < 2097152) { src = x; dst = xb; idx = i; }
    else {
        int j = i - 2097152;
        int sel = j >> 20;
        idx = j & 1048575;
        src = (sel == 0) ? wq : (sel == 1) ? wk : (sel == 2) ? wv : wo;
        dst = (sel == 0) ? oq : (sel == 1) ? ok : (sel == 2) ? ov : oo;
    }
    f32x4 v = ((const f32x4*)src)[idx];
    u16x4 o;
    o[0] = f2bf(v[0]); o[1] = f2bf(v[1]); o[2] = f2bf(v[2]); o[3] = f2bf(v[3]);
    ((u16x4*)dst)[idx] = o;
}

// ---------------------------------------------------------------------------
// HW-verified (R4 probe) ring-3 GEMM: C[m][n] = sum_k A[m][k]*B[n][k].
// MODE 1: bf16 (b,h,d,s). MODE 3: f32 row-major. MODE 6: (b,h,s,d)+RoPE.
template <int MODE>
__global__ __launch_bounds__(256) void gemm_ring(const u16* __restrict__ A,
                                                 const u16* __restrict__ B,
                                                 void* __restrict__ Cout,
                                                 int M, int N, int K,
                                                 const float* __restrict__ ct,
                                                 const float* __restrict__ st) {
    __shared__ __align__(16) u16 As[3 * 4096];
    __shared__ __align__(16) u16 Bs[3 * 4096];
    const int tid  = threadIdx.x;
    const int lane = tid & 63;
    const int wid  = tid >> 6;
    const int wm   = wid >> 1, wn = wid & 1;
    const int nwgx = (int)gridDim.x;
    const int wgid = (int)blockIdx.y * nwgx + (int)blockIdx.x;
    const int cpx  = (nwgx * (int)gridDim.y) >> 3;
    const int swz  = (wgid & 7) * cpx + (wgid >> 3);
    const int m0   = (swz % nwgx) * 128, n0 = (swz / nwgx) * 128;
    const int lr   = lane & 15, lk = lane >> 4;

    const u16* Asrc = A + (size_t)(m0 + (tid >> 2)) * K + (tid & 3) * 8;
    const u16* Bsrc = B + (size_t)(n0 + (tid >> 2)) * K + (tid & 3) * 8;
    const int  dst0 = wid * 512;

    f32x4 acc[4][4] = {};
    const int NT = K >> 5;

#pragma unroll
    for (int i = 0; i < 2; ++i) {
        GLDS(Asrc + (size_t)i * 64 * K,      &As[i * 2048 + dst0]);
        GLDS(Bsrc + (size_t)i * 64 * K,      &Bs[i * 2048 + dst0]);
    }
#pragma unroll
    for (int i = 0; i < 2; ++i) {
        GLDS(Asrc + (size_t)i * 64 * K + 32, &As[4096 + i * 2048 + dst0]);
        GLDS(Bsrc + (size_t)i * 64 * K + 32, &Bs[4096 + i * 2048 + dst0]);
    }

    int buf = 0;
    for (int t = 0; t < NT; ++t) {
        if (t < NT - 1) asm volatile("s_waitcnt vmcnt(4)" ::: "memory");
        else            asm volatile("s_waitcnt vmcnt(0)" ::: "memory");
        __builtin_amdgcn_s_barrier();

        short8 af[4], bf[4];
#pragma unroll
        for (int i = 0; i < 4; ++i)
            af[i] = *(const short8*)&As[buf * 4096 + (wm * 64 + i * 16 + lr) * 32 + lk * 8];
#pragma unroll
        for (int j = 0; j < 4; ++j)
            bf[j] = *(const short8*)&Bs[buf * 4096 + (wn * 64 + j * 16 + lr) * 32 + lk * 8];

        if (t + 2 < NT) {
            int b2 = buf + 2; if (b2 >= 3) b2 -= 3;
            const u16* a2  = Asrc + (size_t)(t + 2) * 32;
            const u16* b2p = Bsrc + (size_t)(t + 2) * 32;
#pragma unroll
            for (int i = 0; i < 2; ++i) {
                GLDS(a2  + (size_t)i * 64 * K, &As[b2 * 4096 + i * 2048 + dst0]);
                GLDS(b2p + (size_t)i * 64 * K, &Bs[b2 * 4096 + i * 2048 + dst0]);
            }
        }

        __builtin_amdgcn_s_setprio(1);
#pragma unroll
        for (int i = 0; i < 4; ++i)
#pragma unroll
            for (int j = 0; j < 4; ++j)
                acc[i][j] = mfma16(af[i], bf[j], acc[i][j]);
        __builtin_amdgcn_s_setprio(0);

        buf = (buf == 2) ? 0 : buf + 1;
    }

#pragma unroll
    for (int i = 0; i < 4; ++i) {
#pragma unroll
        for (int j = 0; j < 4; ++j) {
#pragma unroll
            for (int r = 0; r < 4; ++r) {
                int m = m0 + wm * 64 + i * 16 + lk * 4 + r;
                int n = n0 + wn * 64 + j * 16 + lr;
                float v = acc[i][j][r];
                if (MODE == 1) {        // (b,h,d,s)
                    int h = m >> 7, d = m & (DK - 1), b = n >> 11, s = n & (SEQ - 1);
                    ((u16*)Cout)[(((size_t)(b * NH + h) * DK + d) * SEQ) + s] = f2bf(v);
                } else if (MODE == 6) { // (b,h,s,d) with fused RoPE
                    int b = m >> 11, s = m & (SEQ - 1), h = n >> 7, d = n & (DK - 1);
                    float part = __shfl_xor(v, 1);
                    int ti = (s << 6) + (d >> 1);
                    float c = ct[ti], sn = st[ti];
                    float vr = (lr & 1) ? (v * c + part * sn) : (v * c - part * sn);
                    ((u16*)Cout)[(((size_t)(b * NH + h) * SEQ + s) * DK) + d] = f2bf(vr);
                } else {                // f32 row-major
                    ((float*)Cout)[(size_t)m * N + n] = v;
                }
            }
        }
    }
}

// ---------------------------------------------------------------------------
// R13-HW-verified 2-wave shared-tile flash attention + defer-lsum (R22 best).
__global__ __launch_bounds__(128, 2) void attn_lds2(const u16* __restrict__ Q,
                                                    const u16* __restrict__ K,
                                                    const u16* __restrict__ VT,
                                                    u16* __restrict__ O) {
    const int gid  = blockIdx.x;               // 1024
    const int bh   = (gid & 7) * 4 + ((gid >> 3) & 3);
    const int p    = 31 - (gid >> 5);          // longest first
    const int tid  = threadIdx.x;
    const int w    = tid >> 6;
    const int l    = tid & 63;
    const int q32  = l & 31;
    const int half = l >> 5;
    const int qc   = 2 * p + w;
    const int nt   = 2 * p + 2;
    const int q0   = qc * 32;

    __shared__ __align__(16) u16 Ksh[2][4096];
    __shared__ __align__(16) u16 Vsh[2][4096];

    const u16* Kg  = K  + (size_t)bh * SEQ * DK;
    const u16* VTg = VT + (size_t)bh * DK * SEQ;
    const int b = bh >> 4, h = bh & 15;

    auto stage = [&](int t, int bufn) {
#pragma unroll
        for (int i = 0; i < 4; ++i) {
            int cid = i * 128 + w * 64 + l;
            int kr = cid >> 4, kc = cid & 15;
            GLDS(Kg + (size_t)(t * 32 + kr) * DK + ((kc ^ (kr & 7)) * 8),
                 &Ksh[bufn][(i * 128 + w * 64) * 8]);
            int vr = cid >> 2, vc = cid & 3;
            GLDS(VTg + (size_t)vr * SEQ + t * 32 + ((vc ^ ((vr >> 1) & 3)) * 8),
                 &Vsh[bufn][(i * 128 + w * 64) * 8]);
        }
    };

    short8 qf[8];
    {
        const u16* Qg = Q + ((size_t)bh * SEQ + q0) * DK;
#pragma unroll
        for (int kq = 0; kq < 8; ++kq)
            qf[kq] = *(const short8*)(Qg + q32 * DK + kq * 16 + half * 8);
    }

    f32x16 oacc[4] = {};
    float m = -INFINITY, lsum = 0.f;           // lsum: this half only

    stage(0, 0);
    stage(1, 1);
    for (int t = 0; t < nt; ++t) {
        const int buf = t & 1;
        if (t + 1 < nt) asm volatile("s_waitcnt vmcnt(8)" ::: "memory");
        else            asm volatile("s_waitcnt vmcnt(0)" ::: "memory");
        __builtin_amdgcn_s_barrier();
        __builtin_amdgcn_sched_barrier(0);

        if (t <= qc) {
            const float rs = 0.08838834764831845f;
            short8 kf[8], vf[8];
#pragma unroll
            for (int kq = 0; kq < 8; ++kq) {
                int c = (kq * 2 + half) ^ (q32 & 7);
                kf[kq] = *(const short8*)&Ksh[buf][q32 * 128 + c * 8];
            }
#pragma unroll
            for (int i = 0; i < 8; ++i) {
                int dblk = i >> 1, ch = i & 1;
                int vrow = dblk * 32 + q32;
                int c = (ch * 2 + half) ^ ((q32 >> 1) & 3);
                vf[i] = *(const short8*)&Vsh[buf][vrow * 32 + c * 8];
            }
            const bool diag = (t == qc);

            f32x16 sacc = {};
            __builtin_amdgcn_s_setprio(1);
#pragma unroll
            for (int kq = 0; kq < 8; ++kq) sacc = mfma32(kf[kq], qf[kq], sacc);
            __builtin_amdgcn_s_setprio(0);
#pragma unroll
            for (int r = 0; r < 16; ++r) {
                int kk = (r & 3) + 8 * (r >> 2) + 4 * half;
                float s = sacc[r] * rs;
                if (diag && kk > q32) s = -INFINITY;
                sacc[r] = s;
            }
            float mx[8];
#pragma unroll
            for (int r = 0; r < 8; ++r) mx[r] = fmaxf(sacc[r], sacc[r + 8]);
#pragma unroll
            for (int r = 0; r < 4; ++r) mx[r] = fmaxf(mx[r], mx[r + 4]);
            float tmax = fmaxf(fmaxf(mx[0], mx[1]), fmaxf(mx[2], mx[3]));
            tmax = fmaxf(tmax, __shfl_xor(tmax, 32));
            if (__any(tmax - m > 8.0f)) {
                float mn = fmaxf(m, tmax);
                float sc = __expf(m - mn);
                m = mn; lsum *= sc;
#pragma unroll
                for (int d = 0; d < 4; ++d)
#pragma unroll
                    for (int r = 0; r < 16; ++r) oacc[d][r] *= sc;
            }
#pragma unroll
            for (int r = 0; r < 16; ++r) sacc[r] = __expf(sacc[r] - m);
            float sm[8];
#pragma unroll
            for (int r = 0; r < 8; ++r) sm[r] = sacc[r] + sacc[r + 8];
#pragma unroll
            for (int r = 0; r < 4; ++r) sm[r] = sm[r] + sm[r + 4];
            lsum += (sm[0] + sm[1]) + (sm[2] + sm[3]);   // defer cross-half sum
            u32 pk[8];
#pragma unroll
            for (int i = 0; i < 8; ++i)
                pk[i] = ((u32)f2bf(sacc[2 * i + 1]) << 16) | (u32)f2bf(sacc[2 * i]);
            u32 s0 = __shfl_xor((int)pk[0], 32), s1 = __shfl_xor((int)pk[1], 32);
            u32 s2 = __shfl_xor((int)pk[2], 32), s3 = __shfl_xor((int)pk[3], 32);
            u32 s4 = __shfl_xor((int)pk[4], 32), s5 = __shfl_xor((int)pk[5], 32);
            u32 s6 = __shfl_xor((int)pk[6], 32), s7 = __shfl_xor((int)pk[7], 32);
            union { u32 wd[4]; short8 s8; } P0, P1;
            P0.wd[0] = half ? s2    : pk[0];  P0.wd[1] = half ? s3    : pk[1];
            P0.wd[2] = half ? pk[2] : s0;     P0.wd[3] = half ? pk[3] : s1;
            P1.wd[0] = half ? s6    : pk[4];  P1.wd[1] = half ? s7    : pk[5];
            P1.wd[2] = half ? pk[6] : s4;     P1.wd[3] = half ? pk[7] : s5;
            __builtin_amdgcn_s_setprio(1);
#pragma unroll
            for (int d = 0; d < 4; ++d) {
                oacc[d] = mfma32(vf[2 * d],     P0.s8, oacc[d]);
                oacc[d] = mfma32(vf[2 * d + 1], P1.s8, oacc[d]);
            }
            __builtin_amdgcn_s_setprio(0);
        }

        __builtin_amdgcn_s_barrier();
        if (t + 2 < nt) stage(t + 2, buf);
    }

    lsum += __shfl_xor(lsum, 32);              // combine halves once
    float inv = 1.0f / lsum;
    u16* Og = O + ((size_t)b * SEQ + q0 + q32) * EMB + h * DK;
#pragma unroll
    for (int d = 0; d < 4; ++d)
#pragma unroll
        for (int rq = 0; rq < 4; ++rq) {
            u16x4 o4;
#pragma unroll
            for (int j = 0; j < 4; ++j) o4[j] = f2bf(oacc[d][rq * 4 + j] * inv);
            *(u16x4*)(Og + d * 32 + rq * 8 + half * 4) = o4;
        }
}

// ---------------------------------------------------------------------------
extern "C" void kernel_launch(void* const* d_in, const int* in_sizes, int n_in,
                              void* d_out, int out_size, void* d_ws, size_t ws_size,
                              hipStream_t stream) {
    const float* x    = (const float*)d_in[0];
    const float* wq   = (const float*)d_in[1];
    const float* wk   = (const float*)d_in[2];
    const float* wv   = (const float*)d_in[3];
    const float* wo   = (const float*)d_in[4];
    const float* freq = (const float*)d_in[5];

    char* ws = (char*)d_ws;
    u16*  xb  = (u16*)(ws);                          // 16 MB; later attn output
    u16*  wqb = (u16*)(ws + 16777216);               //  8 MB
    u16*  wkb = (u16*)(ws + 25165824);               //  8 MB
    u16*  wvb = (u16*)(ws + 33554432);               //  8 MB
    u16*  wob = (u16*)(ws + 41943040);               //  8 MB (live till end)
    u16*  Qb  = (u16*)(ws + 50331648);               // 16 MB
    u16*  Kb  = (u16*)(ws + 67108864);               // 16 MB
    u16*  VTb = (u16*)(ws + 83886080);               // 16 MB
    float* ct = (float*)(ws + 100663296);
    float* st = (float*)(ws + 101187584);
    u16*  attn = xb;                                 // x dead after projections

    // casts + rope table, one launch
    cast_all<<<25088, 256, 0, stream>>>(x, wq, wk, wv, wo, freq,
                                        xb, wqb, wkb, wvb, wob, ct, st);

    // serial projections (L2-friendly): Q+RoPE, K+RoPE, V^T
    gemm_ring<6><<<dim3(32, 16), 256, 0, stream>>>(xb,  wqb, Qb,  4096, 2048, 2048, ct, st);
    gemm_ring<6><<<dim3(32, 16), 256, 0, stream>>>(xb,  wkb, Kb,  4096, 2048, 2048, ct, st);
    gemm_ring<1><<<dim3(16, 32), 256, 0, stream>>>(wvb, xb,  VTb, 2048, 4096, 2048, nullptr, nullptr);

    // attention: 2-wave shared-tile, defer-lsum, longest-first
    attn_lds2<<<1024, 128, 0, stream>>>(Qb, Kb, VTb, attn);

    gemm_ring<3><<<dim3(32, 16), 256, 0, stream>>>(attn, wob, d_out, 4096, 2048, 2048, nullptr, nullptr);
}